// Round 19
// baseline (216.645 us; speedup 1.0000x reference)
//
#include <hip/hip_runtime.h>
#include <hip/hip_bf16.h>

typedef __bf16 bf16_t;
typedef __bf16 bf16x8 __attribute__((ext_vector_type(8)));
typedef __bf16 bf16x4 __attribute__((ext_vector_type(4)));
typedef __bf16 bf16x2 __attribute__((ext_vector_type(2)));
typedef float  f32x4  __attribute__((ext_vector_type(4)));

#define HDIM 1024
#define SEQ  2048
#define NHEAD 16
#define HEADD 64

__device__ __forceinline__ void gld_lds16(const void* g, void* l) {
  __builtin_amdgcn_global_load_lds(
      (const __attribute__((address_space(1))) unsigned int*)g,
      (__attribute__((address_space(3))) unsigned int*)l, 16, 0, 0);
}

// native 2^x (v_exp_f32)
__device__ __forceinline__ float fexp2(float x) {
#if __has_builtin(__builtin_amdgcn_exp2f)
  return __builtin_amdgcn_exp2f(x);
#else
  return exp2f(x);
#endif
}

// ---------------- LayerNorm(fp32 in) -> bf16 out ----------------
__global__ __launch_bounds__(256) void ln_kernel(const float* __restrict__ x,
                                                 const float* __restrict__ gam,
                                                 const float* __restrict__ bet,
                                                 bf16_t* __restrict__ out) {
  int row = blockIdx.x;
  int t = threadIdx.x;
  const float4* xr = (const float4*)(x + (size_t)row * HDIM);
  float4 v = xr[t];
  float s = v.x + v.y + v.z + v.w;
  float ss = v.x*v.x + v.y*v.y + v.z*v.z + v.w*v.w;
  #pragma unroll
  for (int o = 32; o > 0; o >>= 1) {
    s  += __shfl_xor(s, o);
    ss += __shfl_xor(ss, o);
  }
  __shared__ float red[8];
  int w = t >> 6;
  if ((t & 63) == 0) { red[w*2] = s; red[w*2+1] = ss; }
  __syncthreads();
  s  = red[0] + red[2] + red[4] + red[6];
  ss = red[1] + red[3] + red[5] + red[7];
  float mu  = s * (1.0f / HDIM);
  float var = ss * (1.0f / HDIM) - mu * mu;
  float rstd = rsqrtf(var + 1e-5f);
  float4 g4 = ((const float4*)gam)[t];
  float4 b4 = ((const float4*)bet)[t];
  bf16x4 o4;
  o4[0] = (bf16_t)((v.x - mu) * rstd * g4.x + b4.x);
  o4[1] = (bf16_t)((v.y - mu) * rstd * g4.y + b4.y);
  o4[2] = (bf16_t)((v.z - mu) * rstd * g4.z + b4.z);
  o4[3] = (bf16_t)((v.w - mu) * rstd * g4.w + b4.w);
  *(bf16x4*)(out + (size_t)row * HDIM + t * 4) = o4;
}

// ---------------- fused prep: weight transposes + LN1 in one dispatch ---------
__global__ __launch_bounds__(256)
void prep_kernel(const float* __restrict__ w_qkv, bf16_t* __restrict__ wqkvT,
                 const float* __restrict__ w_out, bf16_t* __restrict__ woutT,
                 const float* __restrict__ w1,    bf16_t* __restrict__ w1T,
                 const float* __restrict__ w2,    bf16_t* __restrict__ w2T,
                 const float* __restrict__ x,     const float* __restrict__ ln1_g,
                 const float* __restrict__ ln1_b, bf16_t* __restrict__ ln1o) {
  __shared__ float tile[64][65];
  int bid = blockIdx.x;
  int t = threadIdx.x;
  if (bid >= 3072) {
    // ---- LN1 branch ----
    int row = bid - 3072;
    const float4* xr = (const float4*)(x + (size_t)row * HDIM);
    float4 v = xr[t];
    float s = v.x + v.y + v.z + v.w;
    float ss = v.x*v.x + v.y*v.y + v.z*v.z + v.w*v.w;
    #pragma unroll
    for (int o = 32; o > 0; o >>= 1) {
      s  += __shfl_xor(s, o);
      ss += __shfl_xor(ss, o);
    }
    float* red = &tile[0][0];
    int w = t >> 6;
    if ((t & 63) == 0) { red[w*2] = s; red[w*2+1] = ss; }
    __syncthreads();
    s  = red[0] + red[2] + red[4] + red[6];
    ss = red[1] + red[3] + red[5] + red[7];
    float mu  = s * (1.0f / HDIM);
    float var = ss * (1.0f / HDIM) - mu * mu;
    float rstd = rsqrtf(var + 1e-5f);
    float4 g4 = ((const float4*)ln1_g)[t];
    float4 b4 = ((const float4*)ln1_b)[t];
    bf16x4 o4;
    o4[0] = (bf16_t)((v.x - mu) * rstd * g4.x + b4.x);
    o4[1] = (bf16_t)((v.y - mu) * rstd * g4.y + b4.y);
    o4[2] = (bf16_t)((v.z - mu) * rstd * g4.z + b4.z);
    o4[3] = (bf16_t)((v.w - mu) * rstd * g4.w + b4.w);
    *(bf16x4*)(ln1o + (size_t)row * HDIM + t * 4) = o4;
    return;
  }
  // ---- transpose branch ----
  const float* W; bf16_t* Wt; int Kd, Nd, nbx;
  if (bid < 768)        { W = w_qkv; Wt = wqkvT; Kd = 1024; Nd = 3072; nbx = 48; }
  else if (bid < 1024)  { bid -= 768;  W = w_out; Wt = woutT; Kd = 1024; Nd = 1024; nbx = 16; }
  else if (bid < 2048)  { bid -= 1024; W = w1;    Wt = w1T;   Kd = 1024; Nd = 4096; nbx = 64; }
  else                  { bid -= 2048; W = w2;    Wt = w2T;   Kd = 4096; Nd = 1024; nbx = 16; }
  int n0 = (bid % nbx) * 64, k0 = (bid / nbx) * 64;

  int tx = t & 15, ty = t >> 4;
  #pragma unroll
  for (int i = 0; i < 4; i++) {
    float4 v = *(const float4*)(W + (size_t)(k0 + ty + i*16) * Nd + n0 + tx*4);
    tile[ty + i*16][tx*4 + 0] = v.x;
    tile[ty + i*16][tx*4 + 1] = v.y;
    tile[ty + i*16][tx*4 + 2] = v.z;
    tile[ty + i*16][tx*4 + 3] = v.w;
  }
  __syncthreads();
  #pragma unroll
  for (int i = 0; i < 4; i++) {
    int r = ty + i*16;
    bf16x4 o4;
    o4[0] = (bf16_t)tile[tx*4 + 0][r];
    o4[1] = (bf16_t)tile[tx*4 + 1][r];
    o4[2] = (bf16_t)tile[tx*4 + 2][r];
    o4[3] = (bf16_t)tile[tx*4 + 3][r];
    *(bf16x4*)(Wt + (size_t)(n0 + r) * Kd + k0 + tx*4) = o4;
  }
}

// tanh-form GELU, exp2-based
__device__ __forceinline__ float gelu_fast(float x) {
  float y = 0.7978845608f * (x + 0.044715f * x * x * x);
  float u = fexp2(y * 2.885390082f);
  float th = 1.0f - 2.0f * __builtin_amdgcn_rcpf(u + 1.0f);
  return 0.5f * x * (1.0f + th);
}

// ---------------- split-K reduce: out = p0 + p1 + bias + resid (fp32) ----------
__global__ __launch_bounds__(256)
void reduce2_kernel(const bf16_t* __restrict__ p0, const bf16_t* __restrict__ p1,
                    const float* __restrict__ bias, const float* __restrict__ resid,
                    float* __restrict__ out) {
  size_t base = ((size_t)blockIdx.x * 256 + threadIdx.x) * 8;
  bf16x8 a = *(const bf16x8*)(p0 + base);
  bf16x8 b = *(const bf16x8*)(p1 + base);
  int col = (int)(base & (HDIM - 1));
  float4 bi0 = *(const float4*)(bias + col);
  float4 bi1 = *(const float4*)(bias + col + 4);
  float4 r0 = *(const float4*)(resid + base);
  float4 r1 = *(const float4*)(resid + base + 4);
  float4 o0, o1;
  o0.x = (float)a[0] + (float)b[0] + bi0.x + r0.x;
  o0.y = (float)a[1] + (float)b[1] + bi0.y + r0.y;
  o0.z = (float)a[2] + (float)b[2] + bi0.z + r0.z;
  o0.w = (float)a[3] + (float)b[3] + bi0.w + r0.w;
  o1.x = (float)a[4] + (float)b[4] + bi1.x + r1.x;
  o1.y = (float)a[5] + (float)b[5] + bi1.y + r1.y;
  o1.z = (float)a[6] + (float)b[6] + bi1.z + r1.z;
  o1.w = (float)a[7] + (float)b[7] + bi1.w + r1.w;
  *(float4*)(out + base)     = o0;
  *(float4*)(out + base + 4) = o1;
}

// ---------------- GEMM: C[M][N] = A[M][K](bf16) @ Bt[N][K]^T + bias ----------------
// EPI: 0 bias bf16; 1 bias+resid fp32; 2 bias+GELU bf16; 3 split-K partial bf16.
// SWAPPED MFMA operands: acc = mfma(bfr[n], af[m], acc) computes the same C but
// with D-col = C-row, D-row = C-col (m89 layout) -> each lane owns 4 CONSECUTIVE
// C-columns at a fixed row: epilogue uses packed bf16x4/float4 stores and float4
// bias/resid loads (was 64 scalar b16 stores/thread).
// 2-buf LDS, prefetch-before-compute, ONE __syncthreads per K-step (proven).
template<int EPI, int BN, int BK, int WPEU, int SPLITK>
__global__ __launch_bounds__(256, WPEU)
void gemm_bt(const bf16_t* __restrict__ A, const bf16_t* __restrict__ Bt,
             const float* __restrict__ bias, const float* __restrict__ resid,
             void* __restrict__ outp, int M, int N, int K) {
  constexpr int NFRAG = BN / 32;
  constexpr int CH  = BK / 8;
  constexpr int SWZ = CH - 1;
  constexpr int RSH = (BK == 32) ? 1 : 0;
  constexpr int RPP = 256 / CH;
  __shared__ bf16_t As[2][128*BK];
  __shared__ bf16_t Bs[2][BN*BK];
  int t = threadIdx.x;
  int w = t >> 6, l = t & 63;
  int wr = w >> 1, wc = w & 1;

  int nbx = gridDim.x;
  int bid = blockIdx.y * nbx + blockIdx.x;
  int chunkx = (nbx * gridDim.y) >> 3;
  int nb = (bid & 7) * chunkx + (bid >> 3);
  int bm = nb / nbx, bn = nb % nbx;
  size_t m0 = (size_t)bm * 128, n0 = (size_t)bn * BN;

  const int KK = (SPLITK > 1) ? K / SPLITK : K;
  const size_t koff = (SPLITK > 1) ? (size_t)blockIdx.z * KK : 0;

  f32x4 acc[4][NFRAG];
  #pragma unroll
  for (int m = 0; m < 4; m++)
    #pragma unroll
    for (int n = 0; n < NFRAG; n++) acc[m][n] = (f32x4)(0.0f);

  int srow = t / CH;
  int scol = ((t & SWZ) ^ ((srow >> RSH) & SWZ)) * 8;
  int dsto = t * 8;
  const bf16_t* ag = A  + (m0 + srow) * K + koff + scol;
  const bf16_t* bg = Bt + (n0 + srow) * K + koff + scol;

  int lr = l & 15, lg = l >> 4;

  auto stage = [&](int buf, int k0) {
    #pragma unroll
    for (int p = 0; p < 128/RPP; p++)
      gld_lds16(ag + k0 + (size_t)(p*RPP)*K, &As[buf][dsto + p*RPP*BK]);
    #pragma unroll
    for (int p = 0; p < BN/RPP; p++)
      gld_lds16(bg + k0 + (size_t)(p*RPP)*K, &Bs[buf][dsto + p*RPP*BK]);
  };

  stage(0, 0);
  __syncthreads();
  int cur = 0;
  const int NK = KK / BK;
  for (int k = 0; k < NK; k++) {
    if (k + 1 < NK) stage(cur ^ 1, (k + 1) * BK);
    #pragma unroll
    for (int kk = 0; kk < BK/32; kk++) {
      bf16x8 af[4], bfr[NFRAG];
      #pragma unroll
      for (int m = 0; m < 4; m++) {
        int row = wr*64 + m*16 + lr;
        int off = row*BK*2 + (((kk*4 + lg) ^ ((row >> RSH) & SWZ)) << 4);
        af[m] = *(const bf16x8*)((const char*)&As[cur][0] + off);
      }
      #pragma unroll
      for (int n = 0; n < NFRAG; n++) {
        int row = wc*(BN/2) + n*16 + lr;
        int off = row*BK*2 + (((kk*4 + lg) ^ ((row >> RSH) & SWZ)) << 4);
        bfr[n] = *(const bf16x8*)((const char*)&Bs[cur][0] + off);
      }
      #pragma unroll
      for (int m = 0; m < 4; m++)
        #pragma unroll
        for (int n = 0; n < NFRAG; n++)
          acc[m][n] = __builtin_amdgcn_mfma_f32_16x16x32_bf16(bfr[n], af[m], acc[m][n], 0, 0, 0);
    }
    __syncthreads();
    cur ^= 1;
  }

  // swapped-layout epilogue: lane holds C[row = m*16+lr][cols = n*16+lg*4+0..3]
  int cc4 = lg * 4;
  #pragma unroll
  for (int m = 0; m < 4; m++) {
    #pragma unroll
    for (int n = 0; n < NFRAG; n++) {
      size_t row = m0 + wr*64 + m*16 + lr;
      size_t col = n0 + wc*(BN/2) + n*16 + cc4;
      size_t idx = row * (size_t)N + col;
      float4 bv4 = (EPI == 3) ? float4{0,0,0,0} : *(const float4*)(bias + col);
      float v0 = acc[m][n][0] + bv4.x;
      float v1 = acc[m][n][1] + bv4.y;
      float v2 = acc[m][n][2] + bv4.z;
      float v3 = acc[m][n][3] + bv4.w;
      if (EPI == 1) {
        float4 rr = *(const float4*)(resid + idx);
        float4 o4;
        o4.x = v0 + rr.x; o4.y = v1 + rr.y; o4.z = v2 + rr.z; o4.w = v3 + rr.w;
        *(float4*)((float*)outp + idx) = o4;
      } else {
        if (EPI == 2) {
          v0 = gelu_fast(v0); v1 = gelu_fast(v1);
          v2 = gelu_fast(v2); v3 = gelu_fast(v3);
        }
        bf16x4 o4;
        o4[0] = (bf16_t)v0; o4[1] = (bf16_t)v1;
        o4[2] = (bf16_t)v2; o4[3] = (bf16_t)v3;
        bf16_t* dst;
        if (EPI == 3)
          dst = (bf16_t*)(blockIdx.z == 0 ? outp : (void*)resid);
        else
          dst = (bf16_t*)outp;
        *(bf16x4*)(dst + idx) = o4;
      }
    }
  }
}

// ---------------- causal flash attention (swapped-QK^T, per-lane-row softmax) ----
__global__ __launch_bounds__(512, 4)
void attn_kernel(const bf16_t* __restrict__ qkv, bf16_t* __restrict__ out) {
  int idx = blockIdx.x;
  int half = idx >> 8;
  int sub = idx & 255;
  int qth = sub >> 5;
  int qt = half ? qth : (15 - qth);
  int bh = sub & 31;
  int b = bh >> 4, h = bh & 15;
  int t = threadIdx.x, w = t >> 6, l = t & 63;

  __shared__ bf16_t Ks[2][64*64];
  __shared__ bf16_t Vt[2][64*72];
  __shared__ bf16_t Ps[8][16*64];

  const size_t RS = 3 * HDIM;
  const bf16_t* qb = qkv + (size_t)b * SEQ * RS + h * HEADD;
  const bf16_t* kb = qb + HDIM;
  const bf16_t* vb = qb + 2 * HDIM;

  int lr = l & 15, lg = l >> 4;
  const float SCALE = 0.125f * 1.44269504f;

  bf16x8 qf[2];
  {
    size_t qrow = (size_t)qt * 128 + w * 16 + lr;
    qf[0] = *(const bf16x8*)(qb + qrow * RS + lg * 8);
    qf[1] = *(const bf16x8*)(qb + qrow * RS + 32 + lg * 8);
    #pragma unroll
    for (int i = 0; i < 8; i++) {
      qf[0][i] = (bf16_t)((float)qf[0][i] * SCALE);
      qf[1][i] = (bf16_t)((float)qf[1][i] * SCALE);
    }
  }

  f32x4 o[4];
  #pragma unroll
  for (int d = 0; d < 4; d++) o[d] = (f32x4)(0.0f);
  float m = -1e30f, lsum = 0.0f;

  int srow = t >> 3, scol = (t & 7) * 8;
  int Fv = ((scol >> 3) & 7) << 3;
  int nkt = 2 * qt + 2;

  const bf16_t* kg0 = kb + (size_t)srow * RS + scol;
  const bf16_t* vg0 = vb + (size_t)srow * RS + scol;

  bf16x8 kr = *(const bf16x8*)kg0;
  bf16x8 vr = *(const bf16x8*)vg0;

  int wrow0 = qt * 128 + w * 16;
  int qg = wrow0 + lr;
  bf16_t* pw = Ps[w];
  int psw = (lr & 7) << 4;
  int cur = 0;

  for (int kt = 0; kt < nkt; kt++) {
    {
      int ba = srow * 128 + scol * 2;
      int sw = (srow & 7) << 4;
      *(bf16x8*)((char*)Ks[cur] + (ba ^ sw)) = kr;
      int ksw = srow ^ Fv;
      bf16_t* vt = Vt[cur];
      #pragma unroll
      for (int i = 0; i < 8; i++)
        vt[(scol + i) * 72 + ksw] = vr[i];
    }
    if (kt + 1 < nkt) {
      kr = *(const bf16x8*)(kg0 + (size_t)(kt + 1) * 64 * RS);
      vr = *(const bf16x8*)(vg0 + (size_t)(kt + 1) * 64 * RS);
    }
    asm volatile("s_waitcnt lgkmcnt(0)" ::: "memory");
    __builtin_amdgcn_s_barrier();
    __builtin_amdgcn_sched_barrier(0);

    bool skipw = (kt * 64) > (wrow0 + 15);
    if (!skipw) {
      f32x4 sc[4];
      __builtin_amdgcn_s_setprio(1);
      #pragma unroll
      for (int kt2 = 0; kt2 < 4; kt2++) {
        sc[kt2] = (f32x4)(0.0f);
        #pragma unroll
        for (int kk = 0; kk < 2; kk++) {
          int row = kt2 * 16 + lr;
          int off = (row * 128 + kk * 64 + lg * 16) ^ ((row & 7) << 4);
          bf16x8 kf = *(const bf16x8*)((char*)Ks[cur] + off);
          sc[kt2] = __builtin_amdgcn_mfma_f32_16x16x32_bf16(kf, qf[kk], sc[kt2], 0, 0, 0);
        }
      }
      __builtin_amdgcn_s_setprio(0);
      if (kt * 64 + 63 > wrow0) {
        #pragma unroll
        for (int kt2 = 0; kt2 < 4; kt2++) {
          #pragma unroll
          for (int r = 0; r < 4; r++) {
            int kcol = kt*64 + kt2*16 + lg*4 + r;
            if (kcol > qg) sc[kt2][r] = -1e30f;
          }
        }
      }
      // row max via max3-friendly triples (v_max3_f32, T17)
      float u0 = fmaxf(fmaxf(sc[0][0], sc[0][1]), sc[0][2]);
      float u1 = fmaxf(fmaxf(sc[0][3], sc[1][0]), sc[1][1]);
      float u2 = fmaxf(fmaxf(sc[1][2], sc[1][3]), sc[2][0]);
      float u3 = fmaxf(fmaxf(sc[2][1], sc[2][2]), sc[2][3]);
      float u4 = fmaxf(fmaxf(sc[3][0], sc[3][1]), sc[3][2]);
      float tm = fmaxf(fmaxf(fmaxf(u0, u1), u2), fmaxf(fmaxf(u3, u4), sc[3][3]));
      tm = fmaxf(tm, __shfl_xor(tm, 16));
      tm = fmaxf(tm, __shfl_xor(tm, 32));
      if (!__all(tm <= m + 8.0f)) {
        float nm = fmaxf(m, tm);
        float alpha = fexp2(m - nm);
        m = nm;
        lsum *= alpha;
        #pragma unroll
        for (int d = 0; d < 4; d++)
          #pragma unroll
          for (int r = 0; r < 4; r++) o[d][r] *= alpha;
      }
      #pragma unroll
      for (int kt2 = 0; kt2 < 4; kt2++) {
        float p0 = fexp2(sc[kt2][0] - m);
        float p1 = fexp2(sc[kt2][1] - m);
        float p2 = fexp2(sc[kt2][2] - m);
        float p3 = fexp2(sc[kt2][3] - m);
        lsum += (p0 + p1) + (p2 + p3);
        bf16x2 pa; pa[0] = (bf16_t)p0; pa[1] = (bf16_t)p1;
        bf16x2 pb; pb[0] = (bf16_t)p2; pb[1] = (bf16_t)p3;
        int base = lr * 128 + kt2 * 32 + lg * 8;
        *(bf16x2*)((char*)pw + ((base)     ^ psw)) = pa;
        *(bf16x2*)((char*)pw + ((base + 4) ^ psw)) = pb;
      }
      asm volatile("s_waitcnt lgkmcnt(0)" ::: "memory");
      __builtin_amdgcn_s_setprio(1);
      #pragma unroll
      for (int kk = 0; kk < 2; kk++) {
        int poff = (lr * 128 + kk * 64 + lg * 16) ^ psw;
        bf16x8 pf = *(const bf16x8*)((char*)pw + poff);
        #pragma unroll
        for (int dblk = 0; dblk < 4; dblk++) {
          int vrow = dblk * 16 + lr;
          int Fd = ((vrow >> 3) & 7) << 3;
          bf16x8 vf = *(const bf16x8*)(Vt[cur] + vrow * 72 + ((kk * 32 + lg * 8) ^ Fd));
          o[dblk] = __builtin_amdgcn_mfma_f32_16x16x32_bf16(vf, pf, o[dblk], 0, 0, 0);
        }
      }
      __builtin_amdgcn_s_setprio(0);
    }
    cur ^= 1;
  }

  lsum += __shfl_xor(lsum, 16);
  lsum += __shfl_xor(lsum, 32);
  float inv = 1.0f / lsum;

  bf16_t* ob = out + ((size_t)b * SEQ + qg) * HDIM + h * HEADD;
  #pragma unroll
  for (int dblk = 0; dblk < 4; dblk++) {
    bf16x4 q4;
    #pragma unroll
    for (int r = 0; r < 4; r++) q4[r] = (bf16_t)(o[dblk][r] * inv);
    *(bf16x4*)(ob + dblk * 16 + lg * 4) = q4;
  }
}

extern "C" void kernel_launch(void* const* d_in, const int* in_sizes, int n_in,
                              void* d_out, int out_size, void* d_ws, size_t ws_size,
                              hipStream_t stream) {
  (void)in_sizes; (void)n_in; (void)out_size; (void)ws_size;
  const float* x     = (const float*)d_in[0];
  const float* w_qkv = (const float*)d_in[1];
  const float* b_qkv = (const float*)d_in[2];
  const float* w_out = (const float*)d_in[3];
  const float* b_out = (const float*)d_in[4];
  const float* ln1_g = (const float*)d_in[5];
  const float* ln1_b = (const float*)d_in[6];
  const float* ln2_g = (const float*)d_in[7];
  const float* ln2_b = (const float*)d_in[8];
  const float* w1    = (const float*)d_in[9];
  const float* b1    = (const float*)d_in[10];
  const float* w2    = (const float*)d_in[11];
  const float* b2    = (const float*)d_in[12];
  float* out = (float*)d_out;

  char* ws = (char*)d_ws;
  size_t off = 0;
  auto alloc = [&](size_t bytes) -> void* {
    void* p = ws + off;
    off += (bytes + 255) & ~(size_t)255;
    return p;
  };
  bf16_t* wqkvT = (bf16_t*)alloc((size_t)3072*1024*2);
  bf16_t* woutT = (bf16_t*)alloc((size_t)1024*1024*2);
  bf16_t* w1T   = (bf16_t*)alloc((size_t)4096*1024*2);
  bf16_t* w2T   = (bf16_t*)alloc((size_t)1024*4096*2);
  bf16_t* ln1o  = (bf16_t*)alloc((size_t)4096*1024*2);   // reused as h2, then FFN2 part0
  bf16_t* qkvb  = (bf16_t*)alloc((size_t)4096*4096*2);   // qkv, reused as gelu-act
  bf16_t* attno = (bf16_t*)alloc((size_t)4096*1024*2);   // reused as FFN2 part1
  float*  x2    = (float*) alloc((size_t)4096*1024*4);
  bf16_t* h2 = ln1o;
  bf16_t* g  = qkvb;
  bf16_t* part0 = ln1o;
  bf16_t* part1 = attno;

  dim3 blk(256);
  // fused: weight transposes + LN1 (independent inputs) in one dispatch
  prep_kernel<<<7168, blk, 0, stream>>>(w_qkv, wqkvT, w_out, woutT, w1, w1T, w2, w2T,
                                        x, ln1_g, ln1_b, ln1o);
  gemm_bt<0,128,32,4,1><<<dim3(24, 32), blk, 0, stream>>>(ln1o, wqkvT, b_qkv, nullptr, qkvb, 4096, 3072, 1024);
  attn_kernel<<<512, dim3(512), 0, stream>>>(qkvb, attno);
  gemm_bt<1,64,64,2,1><<<dim3(16, 32), blk, 0, stream>>>(attno, woutT, b_out, x, x2, 4096, 1024, 1024);
  ln_kernel<<<4096, blk, 0, stream>>>(x2, ln2_g, ln2_b, h2);
  gemm_bt<2,128,32,4,1><<<dim3(32, 32), blk, 0, stream>>>(h2, w1T, b1, nullptr, g, 4096, 4096, 1024);
  // FFN2 split-K=2 at BN=128/BK=64 (round-14 measured best for this op)
  gemm_bt<3,128,64,2,2><<<dim3(8, 32, 2), blk, 0, stream>>>(g, w2T, b2, (const float*)part1, part0, 4096, 1024, 4096);
  reduce2_kernel<<<2048, blk, 0, stream>>>(part0, part1, b2, x2, out);
}

// Round 20
// 208.953 us; speedup vs baseline: 1.0368x; 1.0368x over previous
//
#include <hip/hip_runtime.h>
#include <hip/hip_bf16.h>

typedef __bf16 bf16_t;
typedef __bf16 bf16x8 __attribute__((ext_vector_type(8)));
typedef __bf16 bf16x4 __attribute__((ext_vector_type(4)));
typedef __bf16 bf16x2 __attribute__((ext_vector_type(2)));
typedef float  f32x4  __attribute__((ext_vector_type(4)));

#define HDIM 1024
#define SEQ  2048
#define NHEAD 16
#define HEADD 64

__device__ __forceinline__ void gld_lds16(const void* g, void* l) {
  __builtin_amdgcn_global_load_lds(
      (const __attribute__((address_space(1))) unsigned int*)g,
      (__attribute__((address_space(3))) unsigned int*)l, 16, 0, 0);
}

// native 2^x (v_exp_f32)
__device__ __forceinline__ float fexp2(float x) {
#if __has_builtin(__builtin_amdgcn_exp2f)
  return __builtin_amdgcn_exp2f(x);
#else
  return exp2f(x);
#endif
}

// ---------------- LayerNorm(fp32 in) -> bf16 out ----------------
__global__ __launch_bounds__(256) void ln_kernel(const float* __restrict__ x,
                                                 const float* __restrict__ gam,
                                                 const float* __restrict__ bet,
                                                 bf16_t* __restrict__ out) {
  int row = blockIdx.x;
  int t = threadIdx.x;
  const float4* xr = (const float4*)(x + (size_t)row * HDIM);
  float4 v = xr[t];
  float s = v.x + v.y + v.z + v.w;
  float ss = v.x*v.x + v.y*v.y + v.z*v.z + v.w*v.w;
  #pragma unroll
  for (int o = 32; o > 0; o >>= 1) {
    s  += __shfl_xor(s, o);
    ss += __shfl_xor(ss, o);
  }
  __shared__ float red[8];
  int w = t >> 6;
  if ((t & 63) == 0) { red[w*2] = s; red[w*2+1] = ss; }
  __syncthreads();
  s  = red[0] + red[2] + red[4] + red[6];
  ss = red[1] + red[3] + red[5] + red[7];
  float mu  = s * (1.0f / HDIM);
  float var = ss * (1.0f / HDIM) - mu * mu;
  float rstd = rsqrtf(var + 1e-5f);
  float4 g4 = ((const float4*)gam)[t];
  float4 b4 = ((const float4*)bet)[t];
  bf16x4 o4;
  o4[0] = (bf16_t)((v.x - mu) * rstd * g4.x + b4.x);
  o4[1] = (bf16_t)((v.y - mu) * rstd * g4.y + b4.y);
  o4[2] = (bf16_t)((v.z - mu) * rstd * g4.z + b4.z);
  o4[3] = (bf16_t)((v.w - mu) * rstd * g4.w + b4.w);
  *(bf16x4*)(out + (size_t)row * HDIM + t * 4) = o4;
}

// ---------------- fused prep: weight transposes + LN1 in one dispatch ---------
__global__ __launch_bounds__(256)
void prep_kernel(const float* __restrict__ w_qkv, bf16_t* __restrict__ wqkvT,
                 const float* __restrict__ w_out, bf16_t* __restrict__ woutT,
                 const float* __restrict__ w1,    bf16_t* __restrict__ w1T,
                 const float* __restrict__ w2,    bf16_t* __restrict__ w2T,
                 const float* __restrict__ x,     const float* __restrict__ ln1_g,
                 const float* __restrict__ ln1_b, bf16_t* __restrict__ ln1o) {
  __shared__ float tile[64][65];
  int bid = blockIdx.x;
  int t = threadIdx.x;
  if (bid >= 3072) {
    // ---- LN1 branch ----
    int row = bid - 3072;
    const float4* xr = (const float4*)(x + (size_t)row * HDIM);
    float4 v = xr[t];
    float s = v.x + v.y + v.z + v.w;
    float ss = v.x*v.x + v.y*v.y + v.z*v.z + v.w*v.w;
    #pragma unroll
    for (int o = 32; o > 0; o >>= 1) {
      s  += __shfl_xor(s, o);
      ss += __shfl_xor(ss, o);
    }
    float* red = &tile[0][0];
    int w = t >> 6;
    if ((t & 63) == 0) { red[w*2] = s; red[w*2+1] = ss; }
    __syncthreads();
    s  = red[0] + red[2] + red[4] + red[6];
    ss = red[1] + red[3] + red[5] + red[7];
    float mu  = s * (1.0f / HDIM);
    float var = ss * (1.0f / HDIM) - mu * mu;
    float rstd = rsqrtf(var + 1e-5f);
    float4 g4 = ((const float4*)ln1_g)[t];
    float4 b4 = ((const float4*)ln1_b)[t];
    bf16x4 o4;
    o4[0] = (bf16_t)((v.x - mu) * rstd * g4.x + b4.x);
    o4[1] = (bf16_t)((v.y - mu) * rstd * g4.y + b4.y);
    o4[2] = (bf16_t)((v.z - mu) * rstd * g4.z + b4.z);
    o4[3] = (bf16_t)((v.w - mu) * rstd * g4.w + b4.w);
    *(bf16x4*)(ln1o + (size_t)row * HDIM + t * 4) = o4;
    return;
  }
  // ---- transpose branch ----
  const float* W; bf16_t* Wt; int Kd, Nd, nbx;
  if (bid < 768)        { W = w_qkv; Wt = wqkvT; Kd = 1024; Nd = 3072; nbx = 48; }
  else if (bid < 1024)  { bid -= 768;  W = w_out; Wt = woutT; Kd = 1024; Nd = 1024; nbx = 16; }
  else if (bid < 2048)  { bid -= 1024; W = w1;    Wt = w1T;   Kd = 1024; Nd = 4096; nbx = 64; }
  else                  { bid -= 2048; W = w2;    Wt = w2T;   Kd = 4096; Nd = 1024; nbx = 16; }
  int n0 = (bid % nbx) * 64, k0 = (bid / nbx) * 64;

  int tx = t & 15, ty = t >> 4;
  #pragma unroll
  for (int i = 0; i < 4; i++) {
    float4 v = *(const float4*)(W + (size_t)(k0 + ty + i*16) * Nd + n0 + tx*4);
    tile[ty + i*16][tx*4 + 0] = v.x;
    tile[ty + i*16][tx*4 + 1] = v.y;
    tile[ty + i*16][tx*4 + 2] = v.z;
    tile[ty + i*16][tx*4 + 3] = v.w;
  }
  __syncthreads();
  #pragma unroll
  for (int i = 0; i < 4; i++) {
    int r = ty + i*16;
    bf16x4 o4;
    o4[0] = (bf16_t)tile[tx*4 + 0][r];
    o4[1] = (bf16_t)tile[tx*4 + 1][r];
    o4[2] = (bf16_t)tile[tx*4 + 2][r];
    o4[3] = (bf16_t)tile[tx*4 + 3][r];
    *(bf16x4*)(Wt + (size_t)(n0 + r) * Kd + k0 + tx*4) = o4;
  }
}

// tanh-form GELU, exp2-based
__device__ __forceinline__ float gelu_fast(float x) {
  float y = 0.7978845608f * (x + 0.044715f * x * x * x);
  float u = fexp2(y * 2.885390082f);
  float th = 1.0f - 2.0f * __builtin_amdgcn_rcpf(u + 1.0f);
  return 0.5f * x * (1.0f + th);
}

// ---------------- split-K reduce: out = p0 + p1 + bias + resid (fp32) ----------
__global__ __launch_bounds__(256)
void reduce2_kernel(const bf16_t* __restrict__ p0, const bf16_t* __restrict__ p1,
                    const float* __restrict__ bias, const float* __restrict__ resid,
                    float* __restrict__ out) {
  size_t base = ((size_t)blockIdx.x * 256 + threadIdx.x) * 8;
  bf16x8 a = *(const bf16x8*)(p0 + base);
  bf16x8 b = *(const bf16x8*)(p1 + base);
  int col = (int)(base & (HDIM - 1));
  float4 bi0 = *(const float4*)(bias + col);
  float4 bi1 = *(const float4*)(bias + col + 4);
  float4 r0 = *(const float4*)(resid + base);
  float4 r1 = *(const float4*)(resid + base + 4);
  float4 o0, o1;
  o0.x = (float)a[0] + (float)b[0] + bi0.x + r0.x;
  o0.y = (float)a[1] + (float)b[1] + bi0.y + r0.y;
  o0.z = (float)a[2] + (float)b[2] + bi0.z + r0.z;
  o0.w = (float)a[3] + (float)b[3] + bi0.w + r0.w;
  o1.x = (float)a[4] + (float)b[4] + bi1.x + r1.x;
  o1.y = (float)a[5] + (float)b[5] + bi1.y + r1.y;
  o1.z = (float)a[6] + (float)b[6] + bi1.z + r1.z;
  o1.w = (float)a[7] + (float)b[7] + bi1.w + r1.w;
  *(float4*)(out + base)     = o0;
  *(float4*)(out + base + 4) = o1;
}

// ---------------- GEMM: C[M][N] = A[M][K](bf16) @ Bt[N][K]^T + bias ----------------
// EPI: 0 bias bf16; 1 bias+resid fp32; 2 bias+GELU bf16; 3 split-K partial bf16
//      (blockIdx.z selects outp / resid-as-ptr).
// 2-buf LDS, prefetch-before-compute, ONE __syncthreads per K-step (proven).
// Normal operand order + row-coalesced scalar epilogue (round-19's swapped
// packed-store variant measured -3.5%: per-lane column stores are 2KB-strided).
template<int EPI, int BN, int BK, int WPEU, int SPLITK>
__global__ __launch_bounds__(256, WPEU)
void gemm_bt(const bf16_t* __restrict__ A, const bf16_t* __restrict__ Bt,
             const float* __restrict__ bias, const float* __restrict__ resid,
             void* __restrict__ outp, int M, int N, int K) {
  constexpr int NFRAG = BN / 32;
  constexpr int CH  = BK / 8;
  constexpr int SWZ = CH - 1;
  constexpr int RSH = (BK == 32) ? 1 : 0;
  constexpr int RPP = 256 / CH;
  __shared__ bf16_t As[2][128*BK];
  __shared__ bf16_t Bs[2][BN*BK];
  int t = threadIdx.x;
  int w = t >> 6, l = t & 63;
  int wr = w >> 1, wc = w & 1;

  int nbx = gridDim.x;
  int bid = blockIdx.y * nbx + blockIdx.x;
  int chunkx = (nbx * gridDim.y) >> 3;
  int nb = (bid & 7) * chunkx + (bid >> 3);
  int bm = nb / nbx, bn = nb % nbx;
  size_t m0 = (size_t)bm * 128, n0 = (size_t)bn * BN;

  const int KK = (SPLITK > 1) ? K / SPLITK : K;
  const size_t koff = (SPLITK > 1) ? (size_t)blockIdx.z * KK : 0;

  f32x4 acc[4][NFRAG];
  #pragma unroll
  for (int m = 0; m < 4; m++)
    #pragma unroll
    for (int n = 0; n < NFRAG; n++) acc[m][n] = (f32x4)(0.0f);

  int srow = t / CH;
  int scol = ((t & SWZ) ^ ((srow >> RSH) & SWZ)) * 8;
  int dsto = t * 8;
  const bf16_t* ag = A  + (m0 + srow) * K + koff + scol;
  const bf16_t* bg = Bt + (n0 + srow) * K + koff + scol;

  int lr = l & 15, lg = l >> 4;

  auto stage = [&](int buf, int k0) {
    #pragma unroll
    for (int p = 0; p < 128/RPP; p++)
      gld_lds16(ag + k0 + (size_t)(p*RPP)*K, &As[buf][dsto + p*RPP*BK]);
    #pragma unroll
    for (int p = 0; p < BN/RPP; p++)
      gld_lds16(bg + k0 + (size_t)(p*RPP)*K, &Bs[buf][dsto + p*RPP*BK]);
  };

  stage(0, 0);
  __syncthreads();
  int cur = 0;
  const int NK = KK / BK;
  for (int k = 0; k < NK; k++) {
    if (k + 1 < NK) stage(cur ^ 1, (k + 1) * BK);
    #pragma unroll
    for (int kk = 0; kk < BK/32; kk++) {
      bf16x8 af[4], bfr[NFRAG];
      #pragma unroll
      for (int m = 0; m < 4; m++) {
        int row = wr*64 + m*16 + lr;
        int off = row*BK*2 + (((kk*4 + lg) ^ ((row >> RSH) & SWZ)) << 4);
        af[m] = *(const bf16x8*)((const char*)&As[cur][0] + off);
      }
      #pragma unroll
      for (int n = 0; n < NFRAG; n++) {
        int row = wc*(BN/2) + n*16 + lr;
        int off = row*BK*2 + (((kk*4 + lg) ^ ((row >> RSH) & SWZ)) << 4);
        bfr[n] = *(const bf16x8*)((const char*)&Bs[cur][0] + off);
      }
      #pragma unroll
      for (int m = 0; m < 4; m++)
        #pragma unroll
        for (int n = 0; n < NFRAG; n++)
          acc[m][n] = __builtin_amdgcn_mfma_f32_16x16x32_bf16(af[m], bfr[n], acc[m][n], 0, 0, 0);
    }
    __syncthreads();
    cur ^= 1;
  }

  int r0 = (l >> 4) * 4, c0 = l & 15;
  bf16_t* pd = nullptr;
  if (EPI == 3)
    pd = (bf16_t*)(blockIdx.z == 0 ? outp : (void*)resid);
  #pragma unroll
  for (int m = 0; m < 4; m++) {
    #pragma unroll
    for (int n = 0; n < NFRAG; n++) {
      size_t row = m0 + wr*64 + m*16 + r0;
      size_t col = n0 + wc*(BN/2) + n*16 + c0;
      float bv = (EPI == 3) ? 0.0f : bias[col];
      #pragma unroll
      for (int r = 0; r < 4; r++) {
        float vv = acc[m][n][r] + bv;
        size_t idx = (row + r) * (size_t)N + col;
        if (EPI == 0) {
          ((bf16_t*)outp)[idx] = (bf16_t)vv;
        } else if (EPI == 1) {
          ((float*)outp)[idx] = vv + resid[idx];
        } else if (EPI == 2) {
          ((bf16_t*)outp)[idx] = (bf16_t)gelu_fast(vv);
        } else {
          pd[idx] = (bf16_t)vv;
        }
      }
    }
  }
}

// ---------------- causal flash attention (swapped-QK^T, per-lane-row softmax) ----
__global__ __launch_bounds__(512, 4)
void attn_kernel(const bf16_t* __restrict__ qkv, bf16_t* __restrict__ out) {
  int idx = blockIdx.x;
  int half = idx >> 8;
  int sub = idx & 255;
  int qth = sub >> 5;
  int qt = half ? qth : (15 - qth);
  int bh = sub & 31;
  int b = bh >> 4, h = bh & 15;
  int t = threadIdx.x, w = t >> 6, l = t & 63;

  __shared__ bf16_t Ks[2][64*64];
  __shared__ bf16_t Vt[2][64*72];
  __shared__ bf16_t Ps[8][16*64];

  const size_t RS = 3 * HDIM;
  const bf16_t* qb = qkv + (size_t)b * SEQ * RS + h * HEADD;
  const bf16_t* kb = qb + HDIM;
  const bf16_t* vb = qb + 2 * HDIM;

  int lr = l & 15, lg = l >> 4;
  const float SCALE = 0.125f * 1.44269504f;

  bf16x8 qf[2];
  {
    size_t qrow = (size_t)qt * 128 + w * 16 + lr;
    qf[0] = *(const bf16x8*)(qb + qrow * RS + lg * 8);
    qf[1] = *(const bf16x8*)(qb + qrow * RS + 32 + lg * 8);
    #pragma unroll
    for (int i = 0; i < 8; i++) {
      qf[0][i] = (bf16_t)((float)qf[0][i] * SCALE);
      qf[1][i] = (bf16_t)((float)qf[1][i] * SCALE);
    }
  }

  f32x4 o[4];
  #pragma unroll
  for (int d = 0; d < 4; d++) o[d] = (f32x4)(0.0f);
  float m = -1e30f, lsum = 0.0f;

  int srow = t >> 3, scol = (t & 7) * 8;
  int Fv = ((scol >> 3) & 7) << 3;
  int nkt = 2 * qt + 2;

  const bf16_t* kg0 = kb + (size_t)srow * RS + scol;
  const bf16_t* vg0 = vb + (size_t)srow * RS + scol;

  bf16x8 kr = *(const bf16x8*)kg0;
  bf16x8 vr = *(const bf16x8*)vg0;

  int wrow0 = qt * 128 + w * 16;
  int qg = wrow0 + lr;
  bf16_t* pw = Ps[w];
  int psw = (lr & 7) << 4;
  int cur = 0;

  for (int kt = 0; kt < nkt; kt++) {
    {
      int ba = srow * 128 + scol * 2;
      int sw = (srow & 7) << 4;
      *(bf16x8*)((char*)Ks[cur] + (ba ^ sw)) = kr;
      int ksw = srow ^ Fv;
      bf16_t* vt = Vt[cur];
      #pragma unroll
      for (int i = 0; i < 8; i++)
        vt[(scol + i) * 72 + ksw] = vr[i];
    }
    if (kt + 1 < nkt) {
      kr = *(const bf16x8*)(kg0 + (size_t)(kt + 1) * 64 * RS);
      vr = *(const bf16x8*)(vg0 + (size_t)(kt + 1) * 64 * RS);
    }
    asm volatile("s_waitcnt lgkmcnt(0)" ::: "memory");
    __builtin_amdgcn_s_barrier();
    __builtin_amdgcn_sched_barrier(0);

    bool skipw = (kt * 64) > (wrow0 + 15);
    if (!skipw) {
      f32x4 sc[4];
      __builtin_amdgcn_s_setprio(1);
      #pragma unroll
      for (int kt2 = 0; kt2 < 4; kt2++) {
        sc[kt2] = (f32x4)(0.0f);
        #pragma unroll
        for (int kk = 0; kk < 2; kk++) {
          int row = kt2 * 16 + lr;
          int off = (row * 128 + kk * 64 + lg * 16) ^ ((row & 7) << 4);
          bf16x8 kf = *(const bf16x8*)((char*)Ks[cur] + off);
          sc[kt2] = __builtin_amdgcn_mfma_f32_16x16x32_bf16(kf, qf[kk], sc[kt2], 0, 0, 0);
        }
      }
      __builtin_amdgcn_s_setprio(0);
      if (kt * 64 + 63 > wrow0) {
        #pragma unroll
        for (int kt2 = 0; kt2 < 4; kt2++) {
          #pragma unroll
          for (int r = 0; r < 4; r++) {
            int kcol = kt*64 + kt2*16 + lg*4 + r;
            if (kcol > qg) sc[kt2][r] = -1e30f;
          }
        }
      }
      float tm0 = fmaxf(fmaxf(sc[0][0], sc[0][1]), fmaxf(sc[0][2], sc[0][3]));
      float tm1 = fmaxf(fmaxf(sc[1][0], sc[1][1]), fmaxf(sc[1][2], sc[1][3]));
      float tm2 = fmaxf(fmaxf(sc[2][0], sc[2][1]), fmaxf(sc[2][2], sc[2][3]));
      float tm3 = fmaxf(fmaxf(sc[3][0], sc[3][1]), fmaxf(sc[3][2], sc[3][3]));
      float tm = fmaxf(fmaxf(tm0, tm1), fmaxf(tm2, tm3));
      tm = fmaxf(tm, __shfl_xor(tm, 16));
      tm = fmaxf(tm, __shfl_xor(tm, 32));
      if (!__all(tm <= m + 8.0f)) {
        float nm = fmaxf(m, tm);
        float alpha = fexp2(m - nm);
        m = nm;
        lsum *= alpha;
        #pragma unroll
        for (int d = 0; d < 4; d++)
          #pragma unroll
          for (int r = 0; r < 4; r++) o[d][r] *= alpha;
      }
      #pragma unroll
      for (int kt2 = 0; kt2 < 4; kt2++) {
        float p0 = fexp2(sc[kt2][0] - m);
        float p1 = fexp2(sc[kt2][1] - m);
        float p2 = fexp2(sc[kt2][2] - m);
        float p3 = fexp2(sc[kt2][3] - m);
        lsum += (p0 + p1) + (p2 + p3);
        bf16x2 pa; pa[0] = (bf16_t)p0; pa[1] = (bf16_t)p1;
        bf16x2 pb; pb[0] = (bf16_t)p2; pb[1] = (bf16_t)p3;
        int base = lr * 128 + kt2 * 32 + lg * 8;
        *(bf16x2*)((char*)pw + ((base)     ^ psw)) = pa;
        *(bf16x2*)((char*)pw + ((base + 4) ^ psw)) = pb;
      }
      asm volatile("s_waitcnt lgkmcnt(0)" ::: "memory");
      __builtin_amdgcn_s_setprio(1);
      #pragma unroll
      for (int kk = 0; kk < 2; kk++) {
        int poff = (lr * 128 + kk * 64 + lg * 16) ^ psw;
        bf16x8 pf = *(const bf16x8*)((char*)pw + poff);
        #pragma unroll
        for (int dblk = 0; dblk < 4; dblk++) {
          int vrow = dblk * 16 + lr;
          int Fd = ((vrow >> 3) & 7) << 3;
          bf16x8 vf = *(const bf16x8*)(Vt[cur] + vrow * 72 + ((kk * 32 + lg * 8) ^ Fd));
          o[dblk] = __builtin_amdgcn_mfma_f32_16x16x32_bf16(vf, pf, o[dblk], 0, 0, 0);
        }
      }
      __builtin_amdgcn_s_setprio(0);
    }
    cur ^= 1;
  }

  lsum += __shfl_xor(lsum, 16);
  lsum += __shfl_xor(lsum, 32);
  float inv = 1.0f / lsum;

  bf16_t* ob = out + ((size_t)b * SEQ + qg) * HDIM + h * HEADD;
  #pragma unroll
  for (int dblk = 0; dblk < 4; dblk++) {
    bf16x4 q4;
    #pragma unroll
    for (int r = 0; r < 4; r++) q4[r] = (bf16_t)(o[dblk][r] * inv);
    *(bf16x4*)(ob + dblk * 16 + lg * 4) = q4;
  }
}

extern "C" void kernel_launch(void* const* d_in, const int* in_sizes, int n_in,
                              void* d_out, int out_size, void* d_ws, size_t ws_size,
                              hipStream_t stream) {
  (void)in_sizes; (void)n_in; (void)out_size; (void)ws_size;
  const float* x     = (const float*)d_in[0];
  const float* w_qkv = (const float*)d_in[1];
  const float* b_qkv = (const float*)d_in[2];
  const float* w_out = (const float*)d_in[3];
  const float* b_out = (const float*)d_in[4];
  const float* ln1_g = (const float*)d_in[5];
  const float* ln1_b = (const float*)d_in[6];
  const float* ln2_g = (const float*)d_in[7];
  const float* ln2_b = (const float*)d_in[8];
  const float* w1    = (const float*)d_in[9];
  const float* b1    = (const float*)d_in[10];
  const float* w2    = (const float*)d_in[11];
  const float* b2    = (const float*)d_in[12];
  float* out = (float*)d_out;

  char* ws = (char*)d_ws;
  size_t off = 0;
  auto alloc = [&](size_t bytes) -> void* {
    void* p = ws + off;
    off += (bytes + 255) & ~(size_t)255;
    return p;
  };
  bf16_t* wqkvT = (bf16_t*)alloc((size_t)3072*1024*2);
  bf16_t* woutT = (bf16_t*)alloc((size_t)1024*1024*2);
  bf16_t* w1T   = (bf16_t*)alloc((size_t)4096*1024*2);
  bf16_t* w2T   = (bf16_t*)alloc((size_t)1024*4096*2);
  bf16_t* ln1o  = (bf16_t*)alloc((size_t)4096*1024*2);   // reused as h2, then FFN2 part0
  bf16_t* qkvb  = (bf16_t*)alloc((size_t)4096*4096*2);   // qkv, reused as gelu-act
  bf16_t* attno = (bf16_t*)alloc((size_t)4096*1024*2);   // reused as FFN2 part1
  float*  x2    = (float*) alloc((size_t)4096*1024*4);
  bf16_t* h2 = ln1o;
  bf16_t* g  = qkvb;
  bf16_t* part0 = ln1o;
  bf16_t* part1 = attno;

  dim3 blk(256);
  // fused: weight transposes + LN1 (independent inputs) in one dispatch
  prep_kernel<<<7168, blk, 0, stream>>>(w_qkv, wqkvT, w_out, woutT, w1, w1T, w2, w2T,
                                        x, ln1_g, ln1_b, ln1o);
  gemm_bt<0,128,32,4,1><<<dim3(24, 32), blk, 0, stream>>>(ln1o, wqkvT, b_qkv, nullptr, qkvb, 4096, 3072, 1024);
  attn_kernel<<<512, dim3(512), 0, stream>>>(qkvb, attno);
  gemm_bt<1,64,64,2,1><<<dim3(16, 32), blk, 0, stream>>>(attno, woutT, b_out, x, x2, 4096, 1024, 1024);
  ln_kernel<<<4096, blk, 0, stream>>>(x2, ln2_g, ln2_b, h2);
  gemm_bt<2,128,32,4,1><<<dim3(32, 32), blk, 0, stream>>>(h2, w1T, b1, nullptr, g, 4096, 4096, 1024);
  // FFN2 split-K=2 at BN=128/BK=64 (round-14 measured best for this op)
  gemm_bt<3,128,64,2,2><<<dim3(8, 32, 2), blk, 0, stream>>>(g, w2T, b2, (const float*)part1, part0, 4096, 1024, 4096);
  reduce2_kernel<<<2048, blk, 0, stream>>>(part0, part1, b2, x2, out);
}